// Round 1
// baseline (1028.310 us; speedup 1.0000x reference)
//
#include <hip/hip_runtime.h>
#include <hip/hip_bf16.h>

// LSTMCell fused: g = hx @ W + b  (M=8192, K=2048, N=7*2048), then gate math.
// bf16 MFMA (16x16x32), f32 accumulate, f32 epilogue.
//
// Tiling: BM=256 rows x BN=32 gate-cols per workgroup, all 7 gates fused.
// 8 waves = 4(M) x 2(N); wave tile = 64 rows x 16 cols x 7 gates.
// Accum: 7 gates * 4 Mfrags * f32x4 = 112 VGPR/lane.

#define B_SZ 8192
#define D_SZ 2048
#define H_SZ 2048
#define NG   7
#define NW   (NG * H_SZ)      // 14336
#define BM   256
#define BN   32
#define BK   32
#define NTH  512
#define LDP  40               // BK + 8 pad (bf16 elems); stride 80B = 5*16B
#define NKST (D_SZ / BK)      // 64

typedef __attribute__((ext_vector_type(8))) short bf16x8;
typedef __attribute__((ext_vector_type(4))) float f32x4;

__device__ __forceinline__ ushort f2bf(float f) {
    union { float f; uint32_t u; } v; v.f = f;
    uint32_t u = v.u;
    return (ushort)((u + 0x7FFFu + ((u >> 16) & 1u)) >> 16);  // RNE
}
__device__ __forceinline__ float sigmoidf_(float x) {
    return 1.0f / (1.0f + __expf(-x));
}
__device__ __forceinline__ float tanhf_(float x) {
    float ax = fabsf(x);
    float e = __expf(2.0f * ax);          // inf for big ax -> t=1, no NaN
    float t = 1.0f - 2.0f / (e + 1.0f);
    return copysignf(t, x);
}
__device__ __forceinline__ float softplusf_(float x) {
    return (x > 30.0f) ? x : __logf(1.0f + __expf(x));
}

__global__ __launch_bounds__(NTH, 2) void lstm_fused(
    const float* __restrict__ hx, const float* __restrict__ cx1,
    const float* __restrict__ cx2, const float* __restrict__ dt,
    const float* __restrict__ W, const float* __restrict__ bias,
    float* __restrict__ out)
{
    __shared__ ushort sA[BM * LDP];        // [row][k] bf16
    __shared__ ushort sB[NG * BN * LDP];   // [(g*32+n)][k] bf16 (k contiguous)

    const int tid = threadIdx.x;

    // XCD-chunked swizzle (nwg = 2048, divisible by 8)
    const int nwg = gridDim.x;
    const int cpx = nwg >> 3;
    const int b0  = blockIdx.x;
    const int swz = (b0 & 7) * cpx + (b0 >> 3);
    const int bx  = swz & 31;     // row-block, 32 of them; fast-varying per XCD
    const int by  = swz >> 5;     // gate-col block, 64 of them
    const int gm0 = bx * BM;
    const int n0  = by * BN;

    const int lane = tid & 63;
    const int wid  = tid >> 6;
    const int wm   = wid >> 1;    // 0..3
    const int wn   = wid & 1;     // 0..1
    const int l15  = lane & 15;
    const int lg   = lane >> 4;   // 0..3

    // prefetch registers
    f32x4 pa[4];
    f32x4 pbl[2], pbh[2];
    const bool hasB2 = (tid < 384);   // wave-uniform (wid<6)

    // B unit decomposition: 896 units = 7g * (16 kpairs * 8 nquads)
    const int bc0 = tid;
    const int bg0 = bc0 >> 7, br0 = bc0 & 127, bkp0 = br0 >> 3, bq0 = br0 & 7;
    const int bc1 = tid + 512;
    const int bg1 = bc1 >> 7, br1 = bc1 & 127, bkp1 = br1 >> 3, bq1 = br1 & 7;

    auto issue_loads = [&](int K0) {
        #pragma unroll
        for (int i = 0; i < 4; ++i) {
            int c = tid + i * NTH;          // 0..2047
            int r = c >> 3, q = c & 7;
            pa[i] = *(const f32x4*)(hx + (size_t)(gm0 + r) * D_SZ + K0 + q * 4);
        }
        {
            const float* p = W + (size_t)(K0 + 2 * bkp0) * NW + bg0 * H_SZ + n0 + bq0 * 4;
            pbl[0] = *(const f32x4*)(p);
            pbh[0] = *(const f32x4*)(p + NW);
        }
        if (hasB2) {
            const float* p = W + (size_t)(K0 + 2 * bkp1) * NW + bg1 * H_SZ + n0 + bq1 * 4;
            pbl[1] = *(const f32x4*)(p);
            pbh[1] = *(const f32x4*)(p + NW);
        }
    };

    auto store_lds = [&]() {
        #pragma unroll
        for (int i = 0; i < 4; ++i) {
            int c = tid + i * NTH;
            int r = c >> 3, q = c & 7;
            ushort4 u;
            u.x = f2bf(pa[i][0]); u.y = f2bf(pa[i][1]);
            u.z = f2bf(pa[i][2]); u.w = f2bf(pa[i][3]);
            *(ushort4*)(&sA[r * LDP + q * 4]) = u;
        }
        #pragma unroll
        for (int jj = 0; jj < 4; ++jj) {
            int n = bq0 * 4 + jj;
            uint32_t v = (uint32_t)f2bf(pbl[0][jj]) | ((uint32_t)f2bf(pbh[0][jj]) << 16);
            *(uint32_t*)(&sB[(bg0 * BN + n) * LDP + 2 * bkp0]) = v;
        }
        if (hasB2) {
            #pragma unroll
            for (int jj = 0; jj < 4; ++jj) {
                int n = bq1 * 4 + jj;
                uint32_t v = (uint32_t)f2bf(pbl[1][jj]) | ((uint32_t)f2bf(pbh[1][jj]) << 16);
                *(uint32_t*)(&sB[(bg1 * BN + n) * LDP + 2 * bkp1]) = v;
            }
        }
    };

    // accumulators
    f32x4 acc[NG][4];
    #pragma unroll
    for (int g = 0; g < NG; ++g)
        #pragma unroll
        for (int mf = 0; mf < 4; ++mf)
            acc[g][mf] = (f32x4){0.f, 0.f, 0.f, 0.f};

    // LDS fragment read offsets (ushort index); 16B-aligned
    int aoff[4];
    #pragma unroll
    for (int mf = 0; mf < 4; ++mf)
        aoff[mf] = (wm * 64 + mf * 16 + l15) * LDP + lg * 8;
    int boff[NG];
    #pragma unroll
    for (int g = 0; g < NG; ++g)
        boff[g] = (g * BN + wn * 16 + l15) * LDP + lg * 8;

    issue_loads(0);
    for (int kk = 0; kk < NKST; ++kk) {
        store_lds();
        __syncthreads();
        if (kk + 1 < NKST) issue_loads((kk + 1) * BK);

        bf16x8 af[4];
        #pragma unroll
        for (int mf = 0; mf < 4; ++mf)
            af[mf] = *(const bf16x8*)(&sA[aoff[mf]]);
        #pragma unroll
        for (int g = 0; g < NG; ++g) {
            bf16x8 bfr = *(const bf16x8*)(&sB[boff[g]]);
            #pragma unroll
            for (int mf = 0; mf < 4; ++mf)
                acc[g][mf] = __builtin_amdgcn_mfma_f32_16x16x32_bf16(
                    af[mf], bfr, acc[g][mf], 0, 0, 0);
        }
        __syncthreads();
    }

    // epilogue: all 7 gate pre-activations live in registers
    const size_t BH = (size_t)B_SZ * H_SZ;
    const int j = n0 + wn * 16 + l15;
    float bj[NG];
    #pragma unroll
    for (int g = 0; g < NG; ++g) bj[g] = bias[g * H_SZ + j];

    #pragma unroll
    for (int mf = 0; mf < 4; ++mf) {
        #pragma unroll
        for (int r = 0; r < 4; ++r) {
            int row = gm0 + wm * 64 + mf * 16 + lg * 4 + r;
            float dtv = dt[row];
            float i1 = sigmoidf_(acc[0][mf][r] + bj[0]);
            float i2 = sigmoidf_(acc[1][mf][r] + bj[1]);
            float f1 = sigmoidf_(acc[2][mf][r] + bj[2]);
            float f2 = sigmoidf_(acc[3][mf][r] + bj[3]);
            float o  = sigmoidf_(acc[4][mf][r] + bj[4]);
            float z  = tanhf_(acc[5][mf][r] + bj[5]);
            float dec = softplusf_(acc[6][mf][r] + bj[6]);
            size_t idx = (size_t)row * H_SZ + j;
            float c1 = cx1[idx], c2 = cx2[idx];
            float cy1 = f1 * c1 + i1 * z;
            float cy2 = f2 * c2 + i2 * z;
            float ct  = cy2 + (cy1 - cy2) * __expf(-dec * dtv);
            float ht  = o * tanhf_(ct);
            out[idx]          = cy1;
            out[BH + idx]     = cy2;
            out[2 * BH + idx] = ht;
        }
    }
}

extern "C" void kernel_launch(void* const* d_in, const int* in_sizes, int n_in,
                              void* d_out, int out_size, void* d_ws, size_t ws_size,
                              hipStream_t stream) {
    const float* hx  = (const float*)d_in[0];
    const float* cx1 = (const float*)d_in[1];
    const float* cx2 = (const float*)d_in[2];
    // d_in[3] = tj (unused: t - tj == dt exactly)
    const float* dt  = (const float*)d_in[4];
    const float* W   = (const float*)d_in[5];
    const float* b   = (const float*)d_in[6];
    float* out = (float*)d_out;

    const int nblk = (B_SZ / BM) * (H_SZ / BN);   // 32 * 64 = 2048
    lstm_fused<<<dim3(nblk), dim3(NTH), 0, stream>>>(hx, cx1, cx2, dt, W, b, out);
}